// Round 12
// baseline (183.172 us; speedup 1.0000x reference)
//
#include <hip/hip_runtime.h>
#include <hip/hip_bf16.h>

#define B_ROWS  2048
#define T_DIM   8
#define IN_DIM  1024
#define OUT_DIM 4096
#define NE      12

#define M_TILE 128
#define N_TILE 128
#define K_STEP 32
#define NSTEP  (IN_DIM / K_STEP)
#define PACK_TILES 2          // row-tiles of 128 packed per expert (256 rows)
#define NCB    (OUT_DIM / N_TILE)   // 32 col-blocks

typedef __attribute__((ext_vector_type(8))) short short8;
typedef __attribute__((ext_vector_type(4))) float f32x4;

union S8U { short8 s; unsigned u[4]; };

// two floats -> packed bf16x2 (v_cvt_pk_bf16_f32, RNE)
__device__ __forceinline__ unsigned cvt2(float a, float b) {
  __hip_bfloat162 h = __float22bfloat162_rn(make_float2(a, b));
  union { __hip_bfloat162 h; unsigned u; } c; c.h = h;
  return c.u;
}

// barrier WITHOUT vmcnt drain: ds-write visibility only (T4 pattern)
__device__ __forceinline__ void barrier_lgkm() {
  asm volatile("s_waitcnt lgkmcnt(0)" ::: "memory");
  __builtin_amdgcn_s_barrier();
}

// async global->LDS, 16B/lane: LDS dest = wave-uniform base + lane*16;
// global source address is per-lane.
__device__ __forceinline__ void gload_lds16(const void* g, void* l) {
  __builtin_amdgcn_global_load_lds(
      (const __attribute__((address_space(1))) void*)g,
      (__attribute__((address_space(3))) void*)l, 16, 0, 0);
}

// ---------------- kernel P: transpose Wg[4096][12] -> WgT[12][4096] --------
__global__ __launch_bounds__(256) void wg_transpose(
    const float* __restrict__ Wg, float* __restrict__ wgt)
{
  const int c = blockIdx.x * 256 + threadIdx.x;
  #pragma unroll
  for (int e = 0; e < NE; ++e)
    wgt[(size_t)e * OUT_DIM + c] = Wg[(size_t)c * NE + e];
}

// ---------------- kernel A: gate (round-5 passing version, unchanged) ------
__global__ __launch_bounds__(256) void gate_kernel(
    const float* __restrict__ t, const float* __restrict__ wgt,
    const float* __restrict__ bg, int* __restrict__ counts,
    int* __restrict__ rowlist)
{
  const int b   = blockIdx.x;
  const int tid = threadIdx.x;
  const float* tb = t + (size_t)b * T_DIM * OUT_DIM;

  float4 m[4];
  #pragma unroll
  for (int it = 0; it < 4; ++it) {
    const int c = (tid + it * 256) * 4;
    float4 s = make_float4(0.f, 0.f, 0.f, 0.f);
    #pragma unroll
    for (int tt = 0; tt < T_DIM; ++tt) {
      const float4 v = *(const float4*)(tb + (size_t)tt * OUT_DIM + c);
      s.x += v.x; s.y += v.y; s.z += v.z; s.w += v.w;
    }
    m[it] = make_float4(s.x * 0.125f, s.y * 0.125f, s.z * 0.125f, s.w * 0.125f);
  }

  float part[NE];
  #pragma unroll
  for (int e = 0; e < NE; ++e) {
    float acc = 0.f;
    #pragma unroll
    for (int it = 0; it < 4; ++it) {
      const int c = (tid + it * 256) * 4;
      const float4 w = *(const float4*)(wgt + (size_t)e * OUT_DIM + c);
      acc += m[it].x * w.x; acc += m[it].y * w.y;
      acc += m[it].z * w.z; acc += m[it].w * w.w;
    }
    part[e] = acc;
  }

  double d[NE];
  #pragma unroll
  for (int e = 0; e < NE; ++e) d[e] = (double)part[e];
  #pragma unroll
  for (int off = 32; off > 0; off >>= 1) {
    #pragma unroll
    for (int e = 0; e < NE; ++e) d[e] += __shfl_down(d[e], off, 64);
  }

  __shared__ double wsred[4][NE];
  const int lane = tid & 63, wave = tid >> 6;
  if (lane == 0) {
    #pragma unroll
    for (int e = 0; e < NE; ++e) wsred[wave][e] = d[e];
  }
  __syncthreads();

  if (tid == 0) {
    double best = -1e300; int bi = 0;
    #pragma unroll
    for (int e = 0; e < NE; ++e) {
      const double v = wsred[0][e] + wsred[1][e] + wsred[2][e] + wsred[3][e] + (double)bg[e];
      if (v > best) { best = v; bi = e; }
    }
    const int pos = atomicAdd(&counts[bi], 1);
    rowlist[bi * B_ROWS + pos] = b;
  }
}

// fallback gate (scalar Wg) if workspace can't hold WgT
__global__ __launch_bounds__(256) void gate_fallback(
    const float* __restrict__ t, const float* __restrict__ Wg,
    const float* __restrict__ bg, int* __restrict__ counts,
    int* __restrict__ rowlist)
{
  const int b   = blockIdx.x;
  const int tid = threadIdx.x;
  const float* tb = t + (size_t)b * T_DIM * OUT_DIM;

  float part[NE];
  #pragma unroll
  for (int e = 0; e < NE; ++e) part[e] = 0.f;
  #pragma unroll
  for (int it = 0; it < 4; ++it) {
    const int c = (tid + it * 256) * 4;
    float4 s = make_float4(0.f, 0.f, 0.f, 0.f);
    #pragma unroll
    for (int tt = 0; tt < T_DIM; ++tt) {
      const float4 v = *(const float4*)(tb + (size_t)tt * OUT_DIM + c);
      s.x += v.x; s.y += v.y; s.z += v.z; s.w += v.w;
    }
    const float mm[4] = { s.x * 0.125f, s.y * 0.125f, s.z * 0.125f, s.w * 0.125f };
    #pragma unroll
    for (int j = 0; j < 4; ++j) {
      const float* wg = Wg + (size_t)(c + j) * NE;
      #pragma unroll
      for (int e = 0; e < NE; ++e) part[e] += mm[j] * wg[e];
    }
  }
  double d[NE];
  #pragma unroll
  for (int e = 0; e < NE; ++e) d[e] = (double)part[e];
  #pragma unroll
  for (int off = 32; off > 0; off >>= 1) {
    #pragma unroll
    for (int e = 0; e < NE; ++e) d[e] += __shfl_down(d[e], off, 64);
  }
  __shared__ double wsred[4][NE];
  const int lane = tid & 63, wave = tid >> 6;
  if (lane == 0) {
    #pragma unroll
    for (int e = 0; e < NE; ++e) wsred[wave][e] = d[e];
  }
  __syncthreads();
  if (tid == 0) {
    double best = -1e300; int bi = 0;
    #pragma unroll
    for (int e = 0; e < NE; ++e) {
      const double v = wsred[0][e] + wsred[1][e] + wsred[2][e] + wsred[3][e] + (double)bg[e];
      if (v > best) { best = v; bi = e; }
    }
    const int pos = atomicAdd(&counts[bi], 1);
    rowlist[bi * B_ROWS + pos] = b;
  }
}

// ---------------- kernel X: pack gathered x into bf16 fragment-slot order --
// slot s: row_off = (s>>6)*16 + (s&15), k = it*32 + ((s>>4)&3)*8 + j.
__global__ __launch_bounds__(256) void pack_x(
    const float* __restrict__ x, const int* __restrict__ counts,
    const int* __restrict__ rowlist, short8* __restrict__ pxa)
{
  const int e   = blockIdx.x;
  const int rt  = blockIdx.y;
  const int it  = blockIdx.z;
  const int cnt = counts[e];
  const int row0 = rt * M_TILE;
  if (row0 >= cnt) return;
  const int* rl = rowlist + e * B_ROWS;
  const int tid = threadIdx.x;
  const int sg = (tid >> 4) & 3, slr = tid & 15, smb = tid >> 6;

  int g0 = row0 + smb * 16 + slr;        g0 = g0 < cnt ? g0 : cnt - 1;
  int g1 = row0 + (smb + 4) * 16 + slr;  g1 = g1 < cnt ? g1 : cnt - 1;
  const float* xp0 = x + (size_t)rl[g0] * IN_DIM + sg * 8 + it * K_STEP;
  const float* xp1 = x + (size_t)rl[g1] * IN_DIM + sg * 8 + it * K_STEP;

  const float4 a = *(const float4*)xp0, b = *(const float4*)(xp0 + 4);
  const float4 c = *(const float4*)xp1, d = *(const float4*)(xp1 + 4);
  S8U v0, v1;
  v0.u[0] = cvt2(a.x, a.y); v0.u[1] = cvt2(a.z, a.w);
  v0.u[2] = cvt2(b.x, b.y); v0.u[3] = cvt2(b.z, b.w);
  v1.u[0] = cvt2(c.x, c.y); v1.u[1] = cvt2(c.z, c.w);
  v1.u[2] = cvt2(d.x, d.y); v1.u[3] = cvt2(d.z, d.w);

  short8* dst = pxa + ((size_t)(e * PACK_TILES + rt) * NSTEP + it) * 512;
  dst[tid]       = v0.s;
  dst[tid + 256] = v1.s;
}

// ---------------- kernel Y: pack W into bf16 fragment-slot order ------------
// pwb[((e*NCB + cb)*NSTEP + it)*512 + s]: slot s holds bf16
// W[e][it*32 + ((s>>4)&3)*8 + j][cb*128 + (s>>6)*16 + (s&15)], j=0..7.
// Identical slot map to the verified r5 W staging. Each W element read once
// (64 B wave segments); written dense. This moves the gemm's per-step
// scalar-load + cvt chain out of the hot loop, paid once.
__global__ __launch_bounds__(256) void pack_w(
    const float* __restrict__ W, short8* __restrict__ pwb)
{
  const int cb = blockIdx.x;
  const int it = blockIdx.y;
  const int e  = blockIdx.z;
  const int tid = threadIdx.x;
  const int sg = (tid >> 4) & 3, slr = tid & 15, smb = tid >> 6;

  const float* p0 = W + (size_t)e * IN_DIM * OUT_DIM
                      + (size_t)(it * K_STEP + sg * 8) * OUT_DIM
                      + cb * N_TILE + smb * 16 + slr;
  const float* p1 = p0 + 64;   // slot tid+256: smb+4 -> +64 cols

  float w0[8], w1[8];
  #pragma unroll
  for (int j = 0; j < 8; ++j) {
    w0[j] = p0[(size_t)j * OUT_DIM];
    w1[j] = p1[(size_t)j * OUT_DIM];
  }
  S8U v0, v1;
  #pragma unroll
  for (int q = 0; q < 4; ++q) {
    v0.u[q] = cvt2(w0[2 * q], w0[2 * q + 1]);
    v1.u[q] = cvt2(w1[2 * q], w1[2 * q + 1]);
  }
  short8* dst = pwb + ((size_t)(e * NCB + cb) * NSTEP + it) * 512;
  dst[tid]       = v0.s;
  dst[tid + 256] = v1.s;
}

// ---------------- kernel B0: pure-DMA GEMM (A and B via global_load_lds) ----
// K-loop has ZERO VALU work: 4 gload_lds + vmcnt(4) + barrier + 8 ds_read +
// 16 MFMA + barrier per wave per step. Counted vmcnt keeps step n+1's 4 DMAs
// in flight across both barriers. XCD swizzle puts the rt=0/1 blocks of each
// (e,cb) W-slice on the same XCD -> second read L2-hits.
__global__ __launch_bounds__(256) void expert_gemm_dma(
    const float* __restrict__ bias, const int* __restrict__ counts,
    const int* __restrict__ rowlist, const short8* __restrict__ pxa,
    const short8* __restrict__ pwb, float* __restrict__ out)
{
  const int bid = blockIdx.x;                  // [0, 768)
  const int wk  = (bid & 7) * 96 + (bid >> 3); // bijective: XCD k owns [96k,96k+96)
  const int e   = wk >> 6;                     // 64 works per expert
  const int rem = wk & 63;
  const int cb  = rem >> 1;
  const int rt  = rem & 1;                     // rt innermost: pair shares W slice
  const int cnt  = counts[e];
  const int row0 = rt * M_TILE;
  if (row0 >= cnt) return;
  const int c0   = cb * N_TILE;
  const int* rl  = rowlist + e * B_ROWS;

  __shared__ short8 xa[2][512];   // 16 KiB
  __shared__ short8 wb[2][512];   // 16 KiB

  const int tid  = threadIdx.x;
  const int lane = tid & 63;
  const int wave = tid >> 6;

  // per-lane DMA sources: wave w covers slots [w*128, w*128+128)
  const short8* at = pxa + (size_t)(e * PACK_TILES + rt) * NSTEP * 512
                   + wave * 128 + lane;
  const short8* bt = pwb + (size_t)(e * NCB + cb) * NSTEP * 512
                   + wave * 128 + lane;

  const int wm = (wave >> 1) * 64, wn = (wave & 1) * 64;
  const int abase = (wave >> 1) * 256, bbase = (wave & 1) * 256;

  f32x4 acc[4][4];
  #pragma unroll
  for (int m = 0; m < 4; ++m)
    #pragma unroll
    for (int n = 0; n < 4; ++n)
      #pragma unroll
      for (int q = 0; q < 4; ++q) acc[m][n][q] = 0.f;

#define DMA_STEP(IT, BUF)                                               \
  {                                                                     \
    gload_lds16(at + (size_t)(IT) * 512,      &xa[BUF][wave * 128]);    \
    gload_lds16(at + (size_t)(IT) * 512 + 64, &xa[BUF][wave * 128 + 64]); \
    gload_lds16(bt + (size_t)(IT) * 512,      &wb[BUF][wave * 128]);    \
    gload_lds16(bt + (size_t)(IT) * 512 + 64, &wb[BUF][wave * 128 + 64]); \
    __builtin_amdgcn_sched_barrier(0);                                  \
  }

  DMA_STEP(0, 0);

  for (int it = 0; it < NSTEP; ++it) {
    const int buf = it & 1;
    const int itn = (it + 1) & (NSTEP - 1);   // wrap: count stays uniform
    DMA_STEP(itn, buf ^ 1);                   // buf^1 reads finished last iter

    // drain this step's 4 DMAs (oldest); keep itn's 4 in flight
    asm volatile("s_waitcnt vmcnt(4)" ::: "memory");
    __builtin_amdgcn_s_barrier();             // tile visible to all waves

    short8 af[4], bf[4];
    #pragma unroll
    for (int m = 0; m < 4; ++m) af[m] = xa[buf][abase + m * 64 + lane];
    #pragma unroll
    for (int n = 0; n < 4; ++n) bf[n] = wb[buf][bbase + n * 64 + lane];
    #pragma unroll
    for (int m = 0; m < 4; ++m)
      #pragma unroll
      for (int n = 0; n < 4; ++n)
        acc[m][n] = __builtin_amdgcn_mfma_f32_16x16x32_bf16(af[m], bf[n], acc[m][n], 0, 0, 0);

    __builtin_amdgcn_s_barrier();             // all reads of buf done
  }
#undef DMA_STEP

  // epilogue: C/D layout col = lane&15, row = (lane>>4)*4 + r
  const int lr = lane & 15;
  const int lq = (lane >> 4) * 4;
  float bcol[4];
  #pragma unroll
  for (int n = 0; n < 4; ++n)
    bcol[n] = bias[e * OUT_DIM + c0 + wn + n * 16 + lr];

  #pragma unroll
  for (int m = 0; m < 4; ++m) {
    #pragma unroll
    for (int r = 0; r < 4; ++r) {
      const int gidx = row0 + wm + m * 16 + lq + r;
      if (gidx >= cnt) continue;
      const int grow = rl[gidx];
      float* orow = out + (size_t)grow * OUT_DIM;
      #pragma unroll
      for (int n = 0; n < 4; ++n) {
        const int col = c0 + wn + n * 16 + lr;
        orow[col] = acc[m][n][r] + bcol[n];
      }
    }
  }
}

// ---------------- kernel B1: r11 packed-A GEMM (mid fallback) ---------------
__global__ __launch_bounds__(256) void expert_gemm_packed(
    const float* __restrict__ W, const float* __restrict__ bias,
    const int* __restrict__ counts, const int* __restrict__ rowlist,
    const short8* __restrict__ pxa, float* __restrict__ out)
{
  const int e    = blockIdx.z;
  const int cnt  = counts[e];
  const int row0 = blockIdx.y * M_TILE;
  if (row0 >= cnt) return;
  const int c0   = blockIdx.x * N_TILE;
  const int* rl  = rowlist + e * B_ROWS;

  __shared__ short8 xa[2][512];
  __shared__ short8 wb[2][512];

  const int tid  = threadIdx.x;
  const int lane = tid & 63;
  const int wave = tid >> 6;
  const int sg = (tid >> 4) & 3, slr = tid & 15, smb = tid >> 6;

  const float* wp = W + (size_t)e * IN_DIM * OUT_DIM
                      + (size_t)(sg * 8) * OUT_DIM + c0 + smb * 16 + slr;
  const short8* at = pxa + (size_t)(e * PACK_TILES + blockIdx.y) * NSTEP * 512
                   + wave * 128 + lane;

  const int wm = (wave >> 1) * 64, wn = (wave & 1) * 64;
  const int abase = (wave >> 1) * 256, bbase = (wave & 1) * 256;

  f32x4 acc[4][4];
  #pragma unroll
  for (int m = 0; m < 4; ++m)
    #pragma unroll
    for (int n = 0; n < 4; ++n)
      #pragma unroll
      for (int q = 0; q < 4; ++q) acc[m][n][q] = 0.f;

  float w0[8], w1[8];

#define W_ISSUE(K)                                                      \
  {                                                                     \
    const float* p = wp + (size_t)(K) * OUT_DIM;                        \
    _Pragma("unroll")                                                   \
    for (int j = 0; j < 8; ++j) {                                       \
      w0[j] = p[(size_t)j * OUT_DIM];                                   \
      w1[j] = p[(size_t)j * OUT_DIM + 64];                              \
    }                                                                   \
  }

  W_ISSUE(0);
  gload_lds16(at,      &xa[0][wave * 128]);
  gload_lds16(at + 64, &xa[0][wave * 128 + 64]);
  __builtin_amdgcn_sched_barrier(0);

  #pragma unroll 2
  for (int it = 0; it < NSTEP; ++it) {
    const int buf = it & 1;
    S8U bv0, bv1;
    #pragma unroll
    for (int q = 0; q < 4; ++q) {
      bv0.u[q] = cvt2(w0[2 * q], w0[2 * q + 1]);
      bv1.u[q] = cvt2(w1[2 * q], w1[2 * q + 1]);
    }
    const int itn = (it + 1 < NSTEP) ? it + 1 : 0;
    W_ISSUE(itn * K_STEP);

    wb[buf][tid]       = bv0.s;
    wb[buf][tid + 256] = bv1.s;

    asm volatile("s_waitcnt vmcnt(16) lgkmcnt(0)" ::: "memory");
    __builtin_amdgcn_s_barrier();

    gload_lds16(at + (size_t)itn * 512,      &xa[buf ^ 1][wave * 128]);
    gload_lds16(at + (size_t)itn * 512 + 64, &xa[buf ^ 1][wave * 128 + 64]);
    __builtin_amdgcn_sched_barrier(0);

    short8 af[4], bf[4];
    #pragma unroll
    for (int m = 0; m < 4; ++m) af[m] = xa[buf][abase + m * 64 + lane];
    #pragma unroll
    for (int n = 0; n < 4; ++n) bf[n] = wb[buf][bbase + n * 64 + lane];
    #pragma unroll
    for (int m = 0; m < 4; ++m)
      #pragma unroll
      for (int n = 0; n < 4; ++n)
        acc[m][n] = __builtin_amdgcn_mfma_f32_16x16x32_bf16(af[m], bf[n], acc[m][n], 0, 0, 0);
  }
#undef W_ISSUE

  const int lr = lane & 15;
  const int lq = (lane >> 4) * 4;
  float bcol[4];
  #pragma unroll
  for (int n = 0; n < 4; ++n)
    bcol[n] = bias[e * OUT_DIM + c0 + wn + n * 16 + lr];

  #pragma unroll
  for (int m = 0; m < 4; ++m) {
    #pragma unroll
    for (int r = 0; r < 4; ++r) {
      const int gidx = row0 + wm + m * 16 + lq + r;
      if (gidx >= cnt) continue;
      const int grow = rl[gidx];
      float* orow = out + (size_t)grow * OUT_DIM;
      #pragma unroll
      for (int n = 0; n < 4; ++n) {
        const int col = c0 + wn + n * 16 + lr;
        orow[col] = acc[m][n][r] + bcol[n];
      }
    }
  }
}

// ---------------- kernel B2: legacy r5 GEMM (low fallback + cnt>256 catcher)
__global__ __launch_bounds__(256) void expert_gemm_legacy(
    const float* __restrict__ x, const float* __restrict__ W,
    const float* __restrict__ bias, const int* __restrict__ counts,
    const int* __restrict__ rowlist, float* __restrict__ out, int y_off)
{
  const int e    = blockIdx.z;
  const int cnt  = counts[e];
  const int row0 = (blockIdx.y + y_off) * M_TILE;
  if (row0 >= cnt) return;
  const int c0   = blockIdx.x * N_TILE;
  const int* rl  = rowlist + e * B_ROWS;

  __shared__ short8 xa[2][512];
  __shared__ short8 wb[2][512];

  const int tid  = threadIdx.x;
  const int lane = tid & 63;
  const int wave = tid >> 6;
  const int sg  = (tid >> 4) & 3;
  const int slr = tid & 15;
  const int smb = tid >> 6;

  int arow0, arow1;
  {
    const int g0 = row0 + smb * 16 + slr;
    const int g1 = row0 + (smb + 4) * 16 + slr;
    arow0 = rl[g0 < cnt ? g0 : cnt - 1];
    arow1 = rl[g1 < cnt ? g1 : cnt - 1];
  }
  const float* xp0 = x + (size_t)arow0 * IN_DIM + sg * 8;
  const float* xp1 = x + (size_t)arow1 * IN_DIM + sg * 8;
  const float* wp  = W + (size_t)e * IN_DIM * OUT_DIM
                       + (size_t)(sg * 8) * OUT_DIM + c0 + smb * 16 + slr;

  const int wm = (wave >> 1) * 64;
  const int wn = (wave & 1) * 64;
  const int abase = (wave >> 1) * 256;
  const int bbase = (wave & 1) * 256;

  f32x4 acc[4][4];
  #pragma unroll
  for (int m = 0; m < 4; ++m)
    #pragma unroll
    for (int n = 0; n < 4; ++n)
      #pragma unroll
      for (int q = 0; q < 4; ++q) acc[m][n][q] = 0.f;

  float4 a0lo, a0hi, a1lo, a1hi;
  float w0[8], w1[8];

#define ISSUE_LOADS(K)                                                  \
  {                                                                     \
    a0lo = *(const float4*)(xp0 + (K));                                 \
    a0hi = *(const float4*)(xp0 + (K) + 4);                             \
    a1lo = *(const float4*)(xp1 + (K));                                 \
    a1hi = *(const float4*)(xp1 + (K) + 4);                             \
    const float* p = wp + (size_t)(K) * OUT_DIM;                        \
    _Pragma("unroll")                                                   \
    for (int j = 0; j < 8; ++j) {                                       \
      w0[j] = p[(size_t)j * OUT_DIM];                                   \
      w1[j] = p[(size_t)j * OUT_DIM + 64];                              \
    }                                                                   \
  }

  ISSUE_LOADS(0);

  for (int it = 0; it < NSTEP; ++it) {
    S8U av0, av1, bv0, bv1;
    av0.u[0] = cvt2(a0lo.x, a0lo.y); av0.u[1] = cvt2(a0lo.z, a0lo.w);
    av0.u[2] = cvt2(a0hi.x, a0hi.y); av0.u[3] = cvt2(a0hi.z, a0hi.w);
    av1.u[0] = cvt2(a1lo.x, a1lo.y); av1.u[1] = cvt2(a1lo.z, a1lo.w);
    av1.u[2] = cvt2(a1hi.x, a1hi.y); av1.u[3] = cvt2(a1hi.z, a1hi.w);
    #pragma unroll
    for (int q = 0; q < 4; ++q) {
      bv0.u[q] = cvt2(w0[2 * q], w0[2 * q + 1]);
      bv1.u[q] = cvt2(w1[2 * q], w1[2 * q + 1]);
    }

    if (it + 1 < NSTEP) ISSUE_LOADS((it + 1) * K_STEP);

    const int buf = it & 1;
    xa[buf][tid]       = av0.s;
    xa[buf][tid + 256] = av1.s;
    wb[buf][tid]       = bv0.s;
    wb[buf][tid + 256] = bv1.s;
    barrier_lgkm();

    short8 af[4], bf[4];
    #pragma unroll
    for (int m = 0; m < 4; ++m) af[m] = xa[buf][abase + m * 64 + lane];
    #pragma unroll
    for (int n = 0; n < 4; ++n) bf[n] = wb[buf][bbase + n * 64 + lane];
    #pragma unroll
    for (int m = 0; m < 4; ++m)
      #pragma unroll
      for (int n = 0; n < 4; ++n)
        acc[m][n] = __builtin_amdgcn_mfma_f32_16x16x32_bf16(af[m], bf[n], acc[m][n], 0, 0, 0);
  }
#undef ISSUE_LOADS

  const int lr = lane & 15;
  const int lq = (lane >> 4) * 4;
  float bcol[4];
  #pragma unroll
  for (int n = 0; n < 4; ++n)
    bcol[n] = bias[e * OUT_DIM + c0 + wn + n * 16 + lr];

  #pragma unroll
  for (int m = 0; m < 4; ++m) {
    #pragma unroll
    for (int r = 0; r < 4; ++r) {
      const int gidx = row0 + wm + m * 16 + lq + r;
      if (gidx >= cnt) continue;
      const int grow = rl[gidx];
      float* orow = out + (size_t)grow * OUT_DIM;
      #pragma unroll
      for (int n = 0; n < 4; ++n) {
        const int col = c0 + wn + n * 16 + lr;
        orow[col] = acc[m][n][r] + bcol[n];
      }
    }
  }
}

extern "C" void kernel_launch(void* const* d_in, const int* in_sizes, int n_in,
                              void* d_out, int out_size, void* d_ws, size_t ws_size,
                              hipStream_t stream) {
  (void)in_sizes; (void)n_in; (void)out_size;
  const float* x  = (const float*)d_in[0];
  const float* t  = (const float*)d_in[1];
  const float* W  = (const float*)d_in[2];
  const float* bb = (const float*)d_in[3];
  const float* Wg = (const float*)d_in[4];
  const float* bg = (const float*)d_in[5];
  float* out = (float*)d_out;

  char*  base    = (char*)d_ws;
  int*   counts  = (int*)base;                       // 64 B
  int*   rowlist = (int*)(base + 64);                // 98304 B
  float* wgt     = (float*)(base + 98368);           // 196608 B -> ends 294976
  short8* pxa    = (short8*)(base + 295936);         // 6 MB -> ends 6587392
  short8* pwb    = (short8*)(base + 6587392);        // 96 MB
  const size_t need_wgt  = 294976;
  const size_t need_pack = 295936 + (size_t)NE * PACK_TILES * NSTEP * 512 * 16;
  const size_t need_pwb  = 6587392 + (size_t)NE * NCB * NSTEP * 512 * 16;

  hipMemsetAsync(counts, 0, 64, stream);

  const bool has_pwb = (ws_size >= need_pwb);
  if (has_pwb)
    pack_w<<<dim3(NCB, NSTEP, NE), 256, 0, stream>>>(W, pwb);

  if (ws_size >= need_wgt) {
    wg_transpose<<<OUT_DIM / 256, 256, 0, stream>>>(Wg, wgt);
    gate_kernel<<<B_ROWS, 256, 0, stream>>>(t, wgt, bg, counts, rowlist);
  } else {
    gate_fallback<<<B_ROWS, 256, 0, stream>>>(t, Wg, bg, counts, rowlist);
  }

  if (has_pwb) {
    pack_x<<<dim3(NE, PACK_TILES, NSTEP), 256, 0, stream>>>(x, counts, rowlist, pxa);
    expert_gemm_dma<<<dim3(NE * NCB * PACK_TILES, 1, 1), 256, 0, stream>>>(
        bb, counts, rowlist, pxa, pwb, out);
    expert_gemm_legacy<<<dim3(NCB, B_ROWS / M_TILE - PACK_TILES, NE),
                         256, 0, stream>>>(x, W, bb, counts, rowlist, out, PACK_TILES);
  } else if (ws_size >= need_pack) {
    pack_x<<<dim3(NE, PACK_TILES, NSTEP), 256, 0, stream>>>(x, counts, rowlist, pxa);
    expert_gemm_packed<<<dim3(NCB, PACK_TILES, NE), 256, 0, stream>>>(
        W, bb, counts, rowlist, pxa, out);
    expert_gemm_legacy<<<dim3(NCB, B_ROWS / M_TILE - PACK_TILES, NE),
                         256, 0, stream>>>(x, W, bb, counts, rowlist, out, PACK_TILES);
  } else {
    expert_gemm_legacy<<<dim3(NCB, B_ROWS / M_TILE, NE),
                         256, 0, stream>>>(x, W, bb, counts, rowlist, out, 0);
  }
}

// Round 13
// 140.783 us; speedup vs baseline: 1.3011x; 1.3011x over previous
//
#include <hip/hip_runtime.h>
#include <hip/hip_bf16.h>

#define B_ROWS  2048
#define T_DIM   8
#define IN_DIM  1024
#define OUT_DIM 4096
#define NE      12

#define M_TILE 128
#define N_TILE 128
#define K_STEP 32
#define NSTEP  (IN_DIM / K_STEP)
#define PACK_TILES 2
#define NCB    (OUT_DIM / N_TILE)   // 32

typedef __attribute__((ext_vector_type(8))) short short8;
typedef __attribute__((ext_vector_type(4))) float f32x4;

union S8U { short8 s; unsigned u[4]; };

__device__ __forceinline__ unsigned cvt2(float a, float b) {
  __hip_bfloat162 h = __float22bfloat162_rn(make_float2(a, b));
  union { __hip_bfloat162 h; unsigned u; } c; c.h = h;
  return c.u;
}

__device__ __forceinline__ void barrier_lgkm() {
  asm volatile("s_waitcnt lgkmcnt(0)" ::: "memory");
  __builtin_amdgcn_s_barrier();
}

__device__ __forceinline__ void gload_lds16(const void* g, void* l) {
  __builtin_amdgcn_global_load_lds(
      (const __attribute__((address_space(1))) void*)g,
      (__attribute__((address_space(3))) void*)l, 16, 0, 0);
}

// ---------------- kernel P: transpose Wg[4096][12] -> WgT[12][4096] --------
__global__ __launch_bounds__(256) void wg_transpose(
    const float* __restrict__ Wg, float* __restrict__ wgt)
{
  const int c = blockIdx.x * 256 + threadIdx.x;
  #pragma unroll
  for (int e = 0; e < NE; ++e)
    wgt[(size_t)e * OUT_DIM + c] = Wg[(size_t)c * NE + e];
}

// ---------------- kernel A: gate (proven version, unchanged) ---------------
__global__ __launch_bounds__(256) void gate_kernel(
    const float* __restrict__ t, const float* __restrict__ wgt,
    const float* __restrict__ bg, int* __restrict__ counts,
    int* __restrict__ rowlist)
{
  const int b   = blockIdx.x;
  const int tid = threadIdx.x;
  const float* tb = t + (size_t)b * T_DIM * OUT_DIM;

  float4 m[4];
  #pragma unroll
  for (int it = 0; it < 4; ++it) {
    const int c = (tid + it * 256) * 4;
    float4 s = make_float4(0.f, 0.f, 0.f, 0.f);
    #pragma unroll
    for (int tt = 0; tt < T_DIM; ++tt) {
      const float4 v = *(const float4*)(tb + (size_t)tt * OUT_DIM + c);
      s.x += v.x; s.y += v.y; s.z += v.z; s.w += v.w;
    }
    m[it] = make_float4(s.x * 0.125f, s.y * 0.125f, s.z * 0.125f, s.w * 0.125f);
  }

  float part[NE];
  #pragma unroll
  for (int e = 0; e < NE; ++e) {
    float acc = 0.f;
    #pragma unroll
    for (int it = 0; it < 4; ++it) {
      const int c = (tid + it * 256) * 4;
      const float4 w = *(const float4*)(wgt + (size_t)e * OUT_DIM + c);
      acc += m[it].x * w.x; acc += m[it].y * w.y;
      acc += m[it].z * w.z; acc += m[it].w * w.w;
    }
    part[e] = acc;
  }

  double d[NE];
  #pragma unroll
  for (int e = 0; e < NE; ++e) d[e] = (double)part[e];
  #pragma unroll
  for (int off = 32; off > 0; off >>= 1) {
    #pragma unroll
    for (int e = 0; e < NE; ++e) d[e] += __shfl_down(d[e], off, 64);
  }

  __shared__ double wsred[4][NE];
  const int lane = tid & 63, wave = tid >> 6;
  if (lane == 0) {
    #pragma unroll
    for (int e = 0; e < NE; ++e) wsred[wave][e] = d[e];
  }
  __syncthreads();

  if (tid == 0) {
    double best = -1e300; int bi = 0;
    #pragma unroll
    for (int e = 0; e < NE; ++e) {
      const double v = wsred[0][e] + wsred[1][e] + wsred[2][e] + wsred[3][e] + (double)bg[e];
      if (v > best) { best = v; bi = e; }
    }
    const int pos = atomicAdd(&counts[bi], 1);
    rowlist[bi * B_ROWS + pos] = b;
  }
}

__global__ __launch_bounds__(256) void gate_fallback(
    const float* __restrict__ t, const float* __restrict__ Wg,
    const float* __restrict__ bg, int* __restrict__ counts,
    int* __restrict__ rowlist)
{
  const int b   = blockIdx.x;
  const int tid = threadIdx.x;
  const float* tb = t + (size_t)b * T_DIM * OUT_DIM;

  float part[NE];
  #pragma unroll
  for (int e = 0; e < NE; ++e) part[e] = 0.f;
  #pragma unroll
  for (int it = 0; it < 4; ++it) {
    const int c = (tid + it * 256) * 4;
    float4 s = make_float4(0.f, 0.f, 0.f, 0.f);
    #pragma unroll
    for (int tt = 0; tt < T_DIM; ++tt) {
      const float4 v = *(const float4*)(tb + (size_t)tt * OUT_DIM + c);
      s.x += v.x; s.y += v.y; s.z += v.z; s.w += v.w;
    }
    const float mm[4] = { s.x * 0.125f, s.y * 0.125f, s.z * 0.125f, s.w * 0.125f };
    #pragma unroll
    for (int j = 0; j < 4; ++j) {
      const float* wg = Wg + (size_t)(c + j) * NE;
      #pragma unroll
      for (int e = 0; e < NE; ++e) part[e] += mm[j] * wg[e];
    }
  }
  double d[NE];
  #pragma unroll
  for (int e = 0; e < NE; ++e) d[e] = (double)part[e];
  #pragma unroll
  for (int off = 32; off > 0; off >>= 1) {
    #pragma unroll
    for (int e = 0; e < NE; ++e) d[e] += __shfl_down(d[e], off, 64);
  }
  __shared__ double wsred[4][NE];
  const int lane = tid & 63, wave = tid >> 6;
  if (lane == 0) {
    #pragma unroll
    for (int e = 0; e < NE; ++e) wsred[wave][e] = d[e];
  }
  __syncthreads();
  if (tid == 0) {
    double best = -1e300; int bi = 0;
    #pragma unroll
    for (int e = 0; e < NE; ++e) {
      const double v = wsred[0][e] + wsred[1][e] + wsred[2][e] + wsred[3][e] + (double)bg[e];
      if (v > best) { best = v; bi = e; }
    }
    const int pos = atomicAdd(&counts[bi], 1);
    rowlist[bi * B_ROWS + pos] = b;
  }
}

// ---------------- kernel X: pack gathered x into bf16 fragment-slot order --
__global__ __launch_bounds__(256) void pack_x(
    const float* __restrict__ x, const int* __restrict__ counts,
    const int* __restrict__ rowlist, short8* __restrict__ pxa)
{
  const int e   = blockIdx.x;
  const int rt  = blockIdx.y;
  const int it  = blockIdx.z;
  const int cnt = counts[e];
  const int row0 = rt * M_TILE;
  if (row0 >= cnt) return;
  const int* rl = rowlist + e * B_ROWS;
  const int tid = threadIdx.x;
  const int sg = (tid >> 4) & 3, slr = tid & 15, smb = tid >> 6;

  int g0 = row0 + smb * 16 + slr;        g0 = g0 < cnt ? g0 : cnt - 1;
  int g1 = row0 + (smb + 4) * 16 + slr;  g1 = g1 < cnt ? g1 : cnt - 1;
  const float* xp0 = x + (size_t)rl[g0] * IN_DIM + sg * 8 + it * K_STEP;
  const float* xp1 = x + (size_t)rl[g1] * IN_DIM + sg * 8 + it * K_STEP;

  const float4 a = *(const float4*)xp0, b = *(const float4*)(xp0 + 4);
  const float4 c = *(const float4*)xp1, d = *(const float4*)(xp1 + 4);
  S8U v0, v1;
  v0.u[0] = cvt2(a.x, a.y); v0.u[1] = cvt2(a.z, a.w);
  v0.u[2] = cvt2(b.x, b.y); v0.u[3] = cvt2(b.z, b.w);
  v1.u[0] = cvt2(c.x, c.y); v1.u[1] = cvt2(c.z, c.w);
  v1.u[2] = cvt2(d.x, d.y); v1.u[3] = cvt2(d.z, d.w);

  short8* dst = pxa + ((size_t)(e * PACK_TILES + rt) * NSTEP + it) * 512;
  dst[tid]       = v0.s;
  dst[tid + 256] = v1.s;
}

// ---------------- kernel B8: 8-wave 256x128 GEMM, W read ONCE ---------------
// 512 threads. 384 blocks (e x cb), XCD-swizzled. Per step per wave:
// 2 A-DMA (pxa) + 1 W slot (8 scalar f32 + 4 cvt + ds_write) + 8 ds_read +
// 16 MFMA, counted vmcnt(8) so W(it+1)'s loads fly across the barrier.
// Delivered bytes: W 192 MB (once) + pxa 192 MB (L2-clustered) + out 32 MB.
__global__ __launch_bounds__(512) void expert_gemm8(
    const float* __restrict__ W, const float* __restrict__ bias,
    const int* __restrict__ counts, const int* __restrict__ rowlist,
    const short8* __restrict__ pxa, float* __restrict__ out)
{
  const int bid = blockIdx.x;                   // [0,384)
  const int wk  = (bid & 7) * 48 + (bid >> 3);  // bijective; XCD k: [48k,48k+48)
  const int e   = wk >> 5;                      // 32 col-blocks per expert
  const int cb  = wk & 31;
  const int cnt = counts[e];
  const int c0  = cb * N_TILE;
  const int* rl = rowlist + e * B_ROWS;

  __shared__ short8 xa[2][1024];   // 32 KiB: 256 rows x 32 k
  __shared__ short8 wb[2][512];    // 16 KiB: 128 cols x 32 k

  const int tid  = threadIdx.x;    // 0..511
  const int lane = tid & 63;
  const int wave = tid >> 6;       // 0..7

  // W staging: thread -> slot tid. col = (tid>>6)*16 + (tid&15), k = 8*sg+j
  const int sg = (tid >> 4) & 3, slr = tid & 15, smb = tid >> 6;
  const float* wp = W + (size_t)e * IN_DIM * OUT_DIM
                      + (size_t)(sg * 8) * OUT_DIM + c0 + smb * 16 + slr;

  // A staging: wave w stages xa slots [w*128,(w+1)*128) from pxa slice
  // rt = w>>2, slice-local slots (w&3)*128 + [0,128)
  const short8* at = pxa + (size_t)(e * PACK_TILES + (wave >> 2)) * NSTEP * 512
                   + (wave & 3) * 128 + lane;

  // MFMA geometry: wave w -> rows [(w>>1)*64, +64) x cols [(w&1)*64, +64)
  const int wm = (wave >> 1) * 64;
  const int wn = (wave & 1) * 64;
  const int abase = (wave >> 2) * 512 + ((wave >> 1) & 1) * 256;
  const int bbase = (wave & 1) * 256;

  f32x4 acc[4][4];
  #pragma unroll
  for (int m = 0; m < 4; ++m)
    #pragma unroll
    for (int n = 0; n < 4; ++n)
      #pragma unroll
      for (int q = 0; q < 4; ++q) acc[m][n][q] = 0.f;

  float w0[8];

#define W_ISSUE(K)                                                      \
  {                                                                     \
    const float* p = wp + (size_t)(K) * OUT_DIM;                        \
    _Pragma("unroll")                                                   \
    for (int j = 0; j < 8; ++j) w0[j] = p[(size_t)j * OUT_DIM];         \
  }
#define A_DMA(IT, BUF)                                                  \
  {                                                                     \
    gload_lds16(at + (size_t)(IT) * 512,      &xa[BUF][wave * 128]);    \
    gload_lds16(at + (size_t)(IT) * 512 + 64, &xa[BUF][wave * 128 + 64]); \
    __builtin_amdgcn_sched_barrier(0);                                  \
  }

  W_ISSUE(0);
  A_DMA(0, 0);

  for (int it = 0; it < NSTEP; ++it) {
    const int buf = it & 1;
    const int itn = (it + 1) & (NSTEP - 1);   // wrap keeps vmcnt uniform

    // convert W(it): dep-wait drains the 8 W loads; A(it) DMAs stay in flight
    S8U bv;
    #pragma unroll
    for (int q = 0; q < 4; ++q)
      bv.u[q] = cvt2(w0[2 * q], w0[2 * q + 1]);

    W_ISSUE(itn * K_STEP);        // 8 loads in flight across the barrier
    wb[buf][tid] = bv.s;

    // drain A(it) (2 oldest) + ds_write; keep W(it+1) (8 youngest) in flight
    asm volatile("s_waitcnt vmcnt(8) lgkmcnt(0)" ::: "memory");
    __builtin_amdgcn_s_barrier();

    A_DMA(itn, buf ^ 1);          // safe: all reads of buf^1 completed

    short8 af[4], bf[4];
    #pragma unroll
    for (int m = 0; m < 4; ++m) af[m] = xa[buf][abase + m * 64 + lane];
    #pragma unroll
    for (int n = 0; n < 4; ++n) bf[n] = wb[buf][bbase + n * 64 + lane];
    #pragma unroll
    for (int m = 0; m < 4; ++m)
      #pragma unroll
      for (int n = 0; n < 4; ++n)
        acc[m][n] = __builtin_amdgcn_mfma_f32_16x16x32_bf16(af[m], bf[n], acc[m][n], 0, 0, 0);
  }
#undef W_ISSUE
#undef A_DMA

  // epilogue: C/D layout col = lane&15, row = (lane>>4)*4 + r
  const int lr = lane & 15;
  const int lq = (lane >> 4) * 4;
  float bcol[4];
  #pragma unroll
  for (int n = 0; n < 4; ++n)
    bcol[n] = bias[e * OUT_DIM + c0 + wn + n * 16 + lr];

  #pragma unroll
  for (int m = 0; m < 4; ++m) {
    #pragma unroll
    for (int r = 0; r < 4; ++r) {
      const int gidx = wm + m * 16 + lq + r;
      if (gidx >= cnt) continue;
      const int grow = rl[gidx];
      float* orow = out + (size_t)grow * OUT_DIM;
      #pragma unroll
      for (int n = 0; n < 4; ++n) {
        const int col = c0 + wn + n * 16 + lr;
        orow[col] = acc[m][n][r] + bcol[n];
      }
    }
  }
}

// ---------------- kernel B2: legacy r5 GEMM (fallback + cnt>256 catcher) ----
__global__ __launch_bounds__(256) void expert_gemm_legacy(
    const float* __restrict__ x, const float* __restrict__ W,
    const float* __restrict__ bias, const int* __restrict__ counts,
    const int* __restrict__ rowlist, float* __restrict__ out, int y_off)
{
  const int e    = blockIdx.z;
  const int cnt  = counts[e];
  const int row0 = (blockIdx.y + y_off) * M_TILE;
  if (row0 >= cnt) return;
  const int c0   = blockIdx.x * N_TILE;
  const int* rl  = rowlist + e * B_ROWS;

  __shared__ short8 xa[2][512];
  __shared__ short8 wb[2][512];

  const int tid  = threadIdx.x;
  const int lane = tid & 63;
  const int wave = tid >> 6;
  const int sg  = (tid >> 4) & 3;
  const int slr = tid & 15;
  const int smb = tid >> 6;

  int arow0, arow1;
  {
    const int g0 = row0 + smb * 16 + slr;
    const int g1 = row0 + (smb + 4) * 16 + slr;
    arow0 = rl[g0 < cnt ? g0 : cnt - 1];
    arow1 = rl[g1 < cnt ? g1 : cnt - 1];
  }
  const float* xp0 = x + (size_t)arow0 * IN_DIM + sg * 8;
  const float* xp1 = x + (size_t)arow1 * IN_DIM + sg * 8;
  const float* wp  = W + (size_t)e * IN_DIM * OUT_DIM
                       + (size_t)(sg * 8) * OUT_DIM + c0 + smb * 16 + slr;

  const int wm = (wave >> 1) * 64;
  const int wn = (wave & 1) * 64;
  const int abase = (wave >> 1) * 256;
  const int bbase = (wave & 1) * 256;

  f32x4 acc[4][4];
  #pragma unroll
  for (int m = 0; m < 4; ++m)
    #pragma unroll
    for (int n = 0; n < 4; ++n)
      #pragma unroll
      for (int q = 0; q < 4; ++q) acc[m][n][q] = 0.f;

  float4 a0lo, a0hi, a1lo, a1hi;
  float w0[8], w1[8];

#define ISSUE_LOADS(K)                                                  \
  {                                                                     \
    a0lo = *(const float4*)(xp0 + (K));                                 \
    a0hi = *(const float4*)(xp0 + (K) + 4);                             \
    a1lo = *(const float4*)(xp1 + (K));                                 \
    a1hi = *(const float4*)(xp1 + (K) + 4);                             \
    const float* p = wp + (size_t)(K) * OUT_DIM;                        \
    _Pragma("unroll")                                                   \
    for (int j = 0; j < 8; ++j) {                                       \
      w0[j] = p[(size_t)j * OUT_DIM];                                   \
      w1[j] = p[(size_t)j * OUT_DIM + 64];                              \
    }                                                                   \
  }

  ISSUE_LOADS(0);

  for (int it = 0; it < NSTEP; ++it) {
    S8U av0, av1, bv0, bv1;
    av0.u[0] = cvt2(a0lo.x, a0lo.y); av0.u[1] = cvt2(a0lo.z, a0lo.w);
    av0.u[2] = cvt2(a0hi.x, a0hi.y); av0.u[3] = cvt2(a0hi.z, a0hi.w);
    av1.u[0] = cvt2(a1lo.x, a1lo.y); av1.u[1] = cvt2(a1lo.z, a1lo.w);
    av1.u[2] = cvt2(a1hi.x, a1hi.y); av1.u[3] = cvt2(a1hi.z, a1hi.w);
    #pragma unroll
    for (int q = 0; q < 4; ++q) {
      bv0.u[q] = cvt2(w0[2 * q], w0[2 * q + 1]);
      bv1.u[q] = cvt2(w1[2 * q], w1[2 * q + 1]);
    }

    if (it + 1 < NSTEP) ISSUE_LOADS((it + 1) * K_STEP);

    const int buf = it & 1;
    xa[buf][tid]       = av0.s;
    xa[buf][tid + 256] = av1.s;
    wb[buf][tid]       = bv0.s;
    wb[buf][tid + 256] = bv1.s;
    barrier_lgkm();

    short8 af[4], bf[4];
    #pragma unroll
    for (int m = 0; m < 4; ++m) af[m] = xa[buf][abase + m * 64 + lane];
    #pragma unroll
    for (int n = 0; n < 4; ++n) bf[n] = wb[buf][bbase + n * 64 + lane];
    #pragma unroll
    for (int m = 0; m < 4; ++m)
      #pragma unroll
      for (int n = 0; n < 4; ++n)
        acc[m][n] = __builtin_amdgcn_mfma_f32_16x16x32_bf16(af[m], bf[n], acc[m][n], 0, 0, 0);
  }
#undef ISSUE_LOADS

  const int lr = lane & 15;
  const int lq = (lane >> 4) * 4;
  float bcol[4];
  #pragma unroll
  for (int n = 0; n < 4; ++n)
    bcol[n] = bias[e * OUT_DIM + c0 + wn + n * 16 + lr];

  #pragma unroll
  for (int m = 0; m < 4; ++m) {
    #pragma unroll
    for (int r = 0; r < 4; ++r) {
      const int gidx = row0 + wm + m * 16 + lq + r;
      if (gidx >= cnt) continue;
      const int grow = rl[gidx];
      float* orow = out + (size_t)grow * OUT_DIM;
      #pragma unroll
      for (int n = 0; n < 4; ++n) {
        const int col = c0 + wn + n * 16 + lr;
        orow[col] = acc[m][n][r] + bcol[n];
      }
    }
  }
}

extern "C" void kernel_launch(void* const* d_in, const int* in_sizes, int n_in,
                              void* d_out, int out_size, void* d_ws, size_t ws_size,
                              hipStream_t stream) {
  (void)in_sizes; (void)n_in; (void)out_size;
  const float* x  = (const float*)d_in[0];
  const float* t  = (const float*)d_in[1];
  const float* W  = (const float*)d_in[2];
  const float* bb = (const float*)d_in[3];
  const float* Wg = (const float*)d_in[4];
  const float* bg = (const float*)d_in[5];
  float* out = (float*)d_out;

  char*  base    = (char*)d_ws;
  int*   counts  = (int*)base;                       // 64 B
  int*   rowlist = (int*)(base + 64);                // 98304 B
  float* wgt     = (float*)(base + 98368);           // 196608 B -> ends 294976
  short8* pxa    = (short8*)(base + 295936);         // 6 MB
  const size_t need_wgt  = 294976;
  const size_t need_pack = 295936 + (size_t)NE * PACK_TILES * NSTEP * 512 * 16;

  hipMemsetAsync(counts, 0, 64, stream);
  if (ws_size >= need_wgt) {
    wg_transpose<<<OUT_DIM / 256, 256, 0, stream>>>(Wg, wgt);
    gate_kernel<<<B_ROWS, 256, 0, stream>>>(t, wgt, bg, counts, rowlist);
  } else {
    gate_fallback<<<B_ROWS, 256, 0, stream>>>(t, Wg, bg, counts, rowlist);
  }

  if (ws_size >= need_pack) {
    pack_x<<<dim3(NE, PACK_TILES, NSTEP), 256, 0, stream>>>(x, counts, rowlist, pxa);
    expert_gemm8<<<dim3(NE * NCB, 1, 1), 512, 0, stream>>>(
        W, bb, counts, rowlist, pxa, out);
    // catcher for the (statistically impossible) cnt > 256 tail
    expert_gemm_legacy<<<dim3(NCB, B_ROWS / M_TILE - PACK_TILES, NE),
                         256, 0, stream>>>(x, W, bb, counts, rowlist, out, PACK_TILES);
  } else {
    expert_gemm_legacy<<<dim3(NCB, B_ROWS / M_TILE, NE),
                         256, 0, stream>>>(x, W, bb, counts, rowlist, out, 0);
  }
}